// Round 4
// baseline (319.937 us; speedup 1.0000x reference)
//
#include <hip/hip_runtime.h>

// Problem constants
#define B_    16
#define DIM   128
#define NPTS  16384
#define J_    16
#define K_    128
#define L_    128
#define R_    8
#define M1_   64

typedef float  f32x4 __attribute__((ext_vector_type(4)));
typedef short  s16x8 __attribute__((ext_vector_type(8)));
typedef unsigned short u16;
typedef u16 u16x8 __attribute__((ext_vector_type(8)));
typedef u16 u16x4 __attribute__((ext_vector_type(4)));

__device__ __forceinline__ u16 f2bf(float f) {
    unsigned u = __float_as_uint(f);
    u += 0x7FFFu + ((u >> 16) & 1u);          // round-nearest-even
    return (u16)(u >> 16);
}
__device__ __forceinline__ float bf2f(u16 h) {
    return __uint_as_float(((unsigned)h) << 16);
}
#define MFMA16(a,b,c) __builtin_amdgcn_mfma_f32_16x16x32_bf16((a),(b),(c),0,0,0)

// Workspace byte offsets (~23 MB; ws >= 512 MB per harness fill size)
#define OFF_PARTA 0u           // 8 MB: stageA partials f32 [8][2048][128]
#define OFF_WBT   8388608u     // 4 MB: wbT u16 [128][16384]
#define OFF_HKL   12582912u    // 0.5 MB: Hkl u16 [16][128][128]   ([j][k][l])
#define OFF_W2T   13107200u    // 0.5 MB: W2T u16 [128][2048]      ([o][j*128+i])
#define OFF_XHB   13631488u    // 0.5 MB: xhatb u16 [2048][128]
#define OFF_YB    14155776u    // 0.5 MB: yb u16 [2048][128]
#define OFF_YPB   14680064u    // 8 MB: ypartb u16 [16 j][16 b][128 o][128 k]

// ---------------------------------------------------------------------------
// Merged prep, range-dispatched by blockIdx (uniform per block).
//  [0,1024):     Hkl[j][k][l] = Do*Di*product + lowrank Q
//  [1024,2048):  W2T[o][j*128+i] = weights[i][o][j]
//  [2048,2176):  wbT[l][p] = bf16(wbases[p][l])   (LDS transpose)
__global__ __launch_bounds__(256) void k_prep(
    const float* __restrict__ product, const float* __restrict__ Do,
    const float* __restrict__ Di, const float* __restrict__ A,
    const float* __restrict__ Bm, const float* __restrict__ W,
    const float* __restrict__ wb,
    u16* __restrict__ Hkl, u16* __restrict__ W2T, u16* __restrict__ wbT)
{
    __shared__ u16 sT[128][136];
    const int bid = blockIdx.x, t = threadIdx.x;
    if (bid < 1024) {
        int idx = (bid << 8) | t;
        int j = idx >> 14, k = (idx >> 7) & 127, l = idx & 127;
        float v = Do[j*K_ + k] * Di[j*L_ + l] * product[k*L_ + l];
        if (k < M1_ && l < M1_) {
            float q = 0.f;
            #pragma unroll
            for (int r = 0; r < R_; ++r)
                q += A[(j*R_ + r)*M1_ + k] * Bm[(j*R_ + r)*M1_ + l];
            v += q;
        }
        Hkl[idx] = f2bf(v);
    } else if (bid < 2048) {
        int idx = ((bid - 1024) << 8) | t;
        int o = idx >> 11, ji = idx & 2047, j = ji >> 7, i = ji & 127;
        W2T[idx] = f2bf(W[(i*DIM + o)*J_ + j]);
    } else {
        const int p0 = (bid - 2048) * 128;
        #pragma unroll
        for (int it = 0; it < 16; ++it) {
            int idx = it*256 + t, row = idx >> 5, c4 = (idx & 31) * 4;
            float4 v = *(const float4*)(wb + (size_t)(p0+row)*L_ + c4);
            sT[c4+0][row] = f2bf(v.x); sT[c4+1][row] = f2bf(v.y);
            sT[c4+2][row] = f2bf(v.z); sT[c4+3][row] = f2bf(v.w);
        }
        __syncthreads();
        #pragma unroll
        for (int it = 0; it < 8; ++it) {
            int idx = it*256 + t, l = idx >> 4, pc = (idx & 15) * 8;
            *(u16x8*)(wbT + (size_t)l*NPTS + p0 + pc) = *(const u16x8*)&sT[l][pc];
        }
    }
}

// ---------------------------------------------------------------------------
// Stage A: part[ks][bi][l] = sum_{p in 2048-chunk} x[bi][p]*wbT[l][p]
// grid (32 m-tiles of 64, 8 k-splits), 512 thr (8 waves 2x4, wave-tile 32x32),
// BK=128, register double-buffered global loads.
__global__ __launch_bounds__(512) void k_stageA(
    const float* __restrict__ x, const u16* __restrict__ wbT,
    float* __restrict__ part)
{
    __shared__ u16 sA[64][136];    // [m][p]
    __shared__ u16 sB[128][136];   // [l][p]
    const int t = threadIdx.x, lane = t & 63, wave = t >> 6;
    const int quad = lane >> 4, l16 = lane & 15;
    const int wr = wave >> 2, wc = wave & 3;
    const int m0 = blockIdx.x * 64;
    const size_t pbase = (size_t)blockIdx.y * 2048;

    f32x4 acc[2][2] = {};
    const int ac4 = (t & 31) * 4, arr = t >> 5;    // x: 4 float4/thread
    const int bc8 = (t & 15) * 8, brr = t >> 4;    // wbT: 4 u16x8/thread

    float4 ra[4];
    u16x8  rb[4];
    #pragma unroll
    for (int i = 0; i < 4; ++i) {
        ra[i] = *(const float4*)(x + (size_t)(m0 + arr + 16*i)*NPTS + pbase + ac4);
        rb[i] = *(const u16x8*)(wbT + (size_t)(brr + 32*i)*NPTS + pbase + bc8);
    }

    for (int pc = 0; pc < 2048; pc += 128) {
        #pragma unroll
        for (int i = 0; i < 4; ++i) {
            u16x4 h = { f2bf(ra[i].x), f2bf(ra[i].y), f2bf(ra[i].z), f2bf(ra[i].w) };
            *(u16x4*)&sA[arr + 16*i][ac4] = h;
            *(u16x8*)&sB[brr + 32*i][bc8] = rb[i];
        }
        __syncthreads();
        if (pc + 128 < 2048) {
            #pragma unroll
            for (int i = 0; i < 4; ++i) {
                ra[i] = *(const float4*)(x + (size_t)(m0 + arr + 16*i)*NPTS + pbase + pc + 128 + ac4);
                rb[i] = *(const u16x8*)(wbT + (size_t)(brr + 32*i)*NPTS + pbase + pc + 128 + bc8);
            }
        }
        #pragma unroll
        for (int ks = 0; ks < 4; ++ks) {
            int kb = ks*32 + quad*8;
            s16x8 a0 = *(const s16x8*)&sA[wr*32      + l16][kb];
            s16x8 a1 = *(const s16x8*)&sA[wr*32 + 16 + l16][kb];
            s16x8 b0 = *(const s16x8*)&sB[wc*32      + l16][kb];
            s16x8 b1 = *(const s16x8*)&sB[wc*32 + 16 + l16][kb];
            acc[0][0] = MFMA16(a0, b0, acc[0][0]);
            acc[0][1] = MFMA16(a0, b1, acc[0][1]);
            acc[1][0] = MFMA16(a1, b0, acc[1][0]);
            acc[1][1] = MFMA16(a1, b1, acc[1][1]);
        }
        __syncthreads();
    }
    float* po = part + (size_t)blockIdx.y * (2048*128);
    #pragma unroll
    for (int mt = 0; mt < 2; ++mt)
      #pragma unroll
      for (int r = 0; r < 4; ++r) {
        int row = m0 + wr*32 + mt*16 + quad*4 + r;
        #pragma unroll
        for (int nt = 0; nt < 2; ++nt) {
            int col = wc*32 + nt*16 + l16;
            po[(size_t)row*128 + col] = acc[mt][nt][r];
        }
      }
}

// xhatb[bi][l] = bf16( sum of 8 partials )
__global__ __launch_bounds__(256) void k_reduceA(
    const float* __restrict__ part, u16* __restrict__ xhatb)
{
    int i = blockIdx.x * 1024 + threadIdx.x;
    #pragma unroll
    for (int e = 0; e < 4; ++e, i += 256) {
        float s = 0.f;
        #pragma unroll
        for (int p = 0; p < 8; ++p) s += part[p*262144 + i];
        xhatb[i] = f2bf(s);
    }
}

// ---------------------------------------------------------------------------
// Fused mix: per (b,j) block,
//   phase1: P[k][i] = sum_l Hkl[j][k][l] * xhatb[b*128+i][l]    (MFMA)
//   phase2: ypartb[j][b][o][k] = sum_i W2T[o][j*128+i] * P[k][i] (MFMA)
// P round-trips through LDS (reuses phase-1 buffers). 256 thr, 4 waves 2x2.
__global__ __launch_bounds__(256) void k_mixF(
    const u16* __restrict__ Hkl, const u16* __restrict__ xhatb,
    const u16* __restrict__ W2T, u16* __restrict__ ypartb)
{
    __shared__ u16 sA[128][136];   // phase1: [k][l] Hkl;   phase2: [k][i] P
    __shared__ u16 sB[128][136];   // phase1: [i][l] xhat;  phase2: [o][i] W2T
    const int t = threadIdx.x, lane = t & 63, wave = t >> 6;
    const int quad = lane >> 4, l16 = lane & 15;
    const int wr = wave >> 1, wc = wave & 1;
    const int b = blockIdx.x, j = blockIdx.y;
    const u16* ha = Hkl + j*16384;
    const u16* xb = xhatb + b*16384;

    const int c8 = (t & 15)*8, rr = t >> 4;
    #pragma unroll
    for (int i = 0; i < 8; ++i) {
        int row = rr + 16*i;
        *(u16x8*)&sA[row][c8] = *(const u16x8*)(ha + row*128 + c8);
        *(u16x8*)&sB[row][c8] = *(const u16x8*)(xb + row*128 + c8);
    }
    __syncthreads();

    f32x4 acc1[4][4] = {};
    #pragma unroll
    for (int ks = 0; ks < 4; ++ks) {
        int kb = ks*32 + quad*8;
        s16x8 a[4], bf[4];
        #pragma unroll
        for (int mt = 0; mt < 4; ++mt) a[mt]  = *(const s16x8*)&sA[wr*64 + mt*16 + l16][kb];
        #pragma unroll
        for (int nt = 0; nt < 4; ++nt) bf[nt] = *(const s16x8*)&sB[wc*64 + nt*16 + l16][kb];
        #pragma unroll
        for (int mt = 0; mt < 4; ++mt)
            #pragma unroll
            for (int nt = 0; nt < 4; ++nt)
                acc1[mt][nt] = MFMA16(a[mt], bf[nt], acc1[mt][nt]);
    }
    __syncthreads();   // phase-1 LDS reads done; safe to overwrite

    // P -> sA (bf16), W2T chunk -> sB
    #pragma unroll
    for (int mt = 0; mt < 4; ++mt)
      #pragma unroll
      for (int r = 0; r < 4; ++r) {
        int k = wr*64 + mt*16 + quad*4 + r;
        #pragma unroll
        for (int nt = 0; nt < 4; ++nt)
            sA[k][wc*64 + nt*16 + l16] = f2bf(acc1[mt][nt][r]);
      }
    #pragma unroll
    for (int i = 0; i < 8; ++i) {
        int row = rr + 16*i;
        *(u16x8*)&sB[row][c8] = *(const u16x8*)(W2T + (size_t)row*2048 + j*128 + c8);
    }
    __syncthreads();

    f32x4 acc2[4][4] = {};
    #pragma unroll
    for (int ks = 0; ks < 4; ++ks) {
        int kb = ks*32 + quad*8;
        s16x8 a[4], bf[4];
        #pragma unroll
        for (int mt = 0; mt < 4; ++mt) a[mt]  = *(const s16x8*)&sB[wr*64 + mt*16 + l16][kb];
        #pragma unroll
        for (int nt = 0; nt < 4; ++nt) bf[nt] = *(const s16x8*)&sA[wc*64 + nt*16 + l16][kb];
        #pragma unroll
        for (int mt = 0; mt < 4; ++mt)
            #pragma unroll
            for (int nt = 0; nt < 4; ++nt)
                acc2[mt][nt] = MFMA16(a[mt], bf[nt], acc2[mt][nt]);
    }
    u16* yo = ypartb + ((size_t)(j*16 + b) << 14);
    #pragma unroll
    for (int mt = 0; mt < 4; ++mt)
      #pragma unroll
      for (int r = 0; r < 4; ++r) {
        int o = wr*64 + mt*16 + quad*4 + r;
        #pragma unroll
        for (int nt = 0; nt < 4; ++nt) {
            int k = wc*64 + nt*16 + l16;
            yo[(size_t)o*128 + k] = f2bf(acc2[mt][nt][r]);
        }
      }
}

// yb[bo][k] = bf16( sum of 16 bf16 partials ), vectorized u16x8
__global__ __launch_bounds__(256) void k_reduceY(
    const u16* __restrict__ part, u16* __restrict__ yb)
{
    int i8 = (blockIdx.x * 256 + threadIdx.x) * 8;
    float s[8] = {};
    #pragma unroll
    for (int p = 0; p < 16; ++p) {
        u16x8 v = *(const u16x8*)(part + p*262144 + i8);
        #pragma unroll
        for (int e = 0; e < 8; ++e) s[e] += bf2f(v[e]);
    }
    u16x8 o;
    #pragma unroll
    for (int e = 0; e < 8; ++e) o[e] = f2bf(s[e]);
    *(u16x8*)(yb + i8) = o;
}

// ---------------------------------------------------------------------------
// Stage E: out[bo][p] = sum_k yb[bo][k] * bases[p][k]  (bases f32, inline cvt)
// grid (16 bo-tiles, 128 p-tiles), 256 thr, single-shot K=128
__global__ __launch_bounds__(256) void k_stageE(
    const u16* __restrict__ yb, const float* __restrict__ bases,
    float* __restrict__ out)
{
    __shared__ u16 sA[128][136];   // [bo][k]
    __shared__ u16 sB[128][136];   // [p][k]
    const int t = threadIdx.x, lane = t & 63, wave = t >> 6;
    const int quad = lane >> 4, l16 = lane & 15;
    const int wr = wave >> 1, wc = wave & 1;
    const int bo0 = blockIdx.x * 128, p0 = blockIdx.y * 128;

    const int c8 = (t & 15)*8, rr = t >> 4;
    #pragma unroll
    for (int i = 0; i < 8; ++i) {
        int row = rr + 16*i;
        *(u16x8*)&sA[row][c8] = *(const u16x8*)(yb + (size_t)(bo0+row)*128 + c8);
    }
    const int c4 = (t & 31) * 4, br = t >> 5;
    #pragma unroll
    for (int i = 0; i < 16; ++i) {
        int row = br + 8*i;
        float4 v = *(const float4*)(bases + (size_t)(p0+row)*K_ + c4);
        u16x4 h = { f2bf(v.x), f2bf(v.y), f2bf(v.z), f2bf(v.w) };
        *(u16x4*)&sB[row][c4] = h;
    }
    __syncthreads();

    f32x4 acc[4][4] = {};
    #pragma unroll
    for (int ks = 0; ks < 4; ++ks) {
        int kb = ks*32 + quad*8;
        s16x8 a[4], bf[4];
        #pragma unroll
        for (int mt = 0; mt < 4; ++mt) a[mt]  = *(const s16x8*)&sA[wr*64 + mt*16 + l16][kb];
        #pragma unroll
        for (int nt = 0; nt < 4; ++nt) bf[nt] = *(const s16x8*)&sB[wc*64 + nt*16 + l16][kb];
        #pragma unroll
        for (int mt = 0; mt < 4; ++mt)
            #pragma unroll
            for (int nt = 0; nt < 4; ++nt)
                acc[mt][nt] = MFMA16(a[mt], bf[nt], acc[mt][nt]);
    }
    #pragma unroll
    for (int mt = 0; mt < 4; ++mt)
      #pragma unroll
      for (int r = 0; r < 4; ++r) {
        size_t row = bo0 + wr*64 + mt*16 + quad*4 + r;
        #pragma unroll
        for (int nt = 0; nt < 4; ++nt) {
            int p = p0 + wc*64 + nt*16 + l16;
            out[row*NPTS + p] = acc[mt][nt][r];
        }
      }
}

// ---------------------------------------------------------------------------
extern "C" void kernel_launch(void* const* d_in, const int* in_sizes, int n_in,
                              void* d_out, int out_size, void* d_ws, size_t ws_size,
                              hipStream_t stream) {
    (void)in_sizes; (void)n_in; (void)out_size; (void)ws_size;
    const float* x       = (const float*)d_in[0];
    const float* bases   = (const float*)d_in[1];
    const float* wbases  = (const float*)d_in[2];
    const float* product = (const float*)d_in[3];
    const float* Do      = (const float*)d_in[4];
    const float* Di      = (const float*)d_in[5];
    const float* A       = (const float*)d_in[6];
    const float* Bm      = (const float*)d_in[7];
    const float* W       = (const float*)d_in[8];

    char* ws = (char*)d_ws;
    float* partA  = (float*)(ws + OFF_PARTA);
    u16*   wbT    = (u16*)  (ws + OFF_WBT);
    u16*   Hkl    = (u16*)  (ws + OFF_HKL);
    u16*   W2T    = (u16*)  (ws + OFF_W2T);
    u16*   xhatb  = (u16*)  (ws + OFF_XHB);
    u16*   yb     = (u16*)  (ws + OFF_YB);
    u16*   ypartb = (u16*)  (ws + OFF_YPB);

    k_prep   <<<2176, 256, 0, stream>>>(product, Do, Di, A, Bm, W, wbases,
                                        Hkl, W2T, wbT);
    k_stageA <<<dim3(32, 8), 512, 0, stream>>>(x, wbT, partA);
    k_reduceA<<<256, 256, 0, stream>>>(partA, xhatb);
    k_mixF   <<<dim3(16, 16), 256, 0, stream>>>(Hkl, xhatb, W2T, ypartb);
    k_reduceY<<<128, 256, 0, stream>>>(ypartb, yb);
    k_stageE <<<dim3(16, 128), 256, 0, stream>>>(yb, bases, (float*)d_out);
}

// Round 5
// 317.046 us; speedup vs baseline: 1.0091x; 1.0091x over previous
//
#include <hip/hip_runtime.h>

// Problem constants
#define B_    16
#define DIM   128
#define NPTS  16384
#define J_    16
#define K_    128
#define L_    128
#define R_    8
#define M1_   64

typedef float  f32x4 __attribute__((ext_vector_type(4)));
typedef short  s16x8 __attribute__((ext_vector_type(8)));
typedef unsigned short u16;
typedef u16 u16x8 __attribute__((ext_vector_type(8)));
typedef u16 u16x4 __attribute__((ext_vector_type(4)));

__device__ __forceinline__ u16 f2bf(float f) {
    unsigned u = __float_as_uint(f);
    u += 0x7FFFu + ((u >> 16) & 1u);          // round-nearest-even
    return (u16)(u >> 16);
}
__device__ __forceinline__ float bf2f(u16 h) {
    return __uint_as_float(((unsigned)h) << 16);
}
#define MFMA16(a,b,c) __builtin_amdgcn_mfma_f32_16x16x32_bf16((a),(b),(c),0,0,0)

// Workspace byte offsets (~23 MB; ws >= 512 MB per harness fill size)
#define OFF_PARTA 0u           // 8 MB: stageA partials f32 [8][2048][128]
#define OFF_WBT   8388608u     // 4 MB: wbT u16 [128][16384]
#define OFF_HKL   12582912u    // 0.5 MB: Hkl u16 [16][128][128]   ([j][k][l])
#define OFF_W2T   13107200u    // 0.5 MB: W2T u16 [128][2048]      ([o][j*128+i])
#define OFF_XHB   13631488u    // 0.5 MB: xhatb u16 [2048][128]
#define OFF_YB    14155776u    // 0.5 MB: yb u16 [2048][128]
#define OFF_YPB   14680064u    // 8 MB: ypartb u16 [16 j][16 b][128 o][128 k]

// ---------------------------------------------------------------------------
// Merged prep, range-dispatched by blockIdx (uniform per block).
__global__ __launch_bounds__(256) void k_prep(
    const float* __restrict__ product, const float* __restrict__ Do,
    const float* __restrict__ Di, const float* __restrict__ A,
    const float* __restrict__ Bm, const float* __restrict__ W,
    const float* __restrict__ wb,
    u16* __restrict__ Hkl, u16* __restrict__ W2T, u16* __restrict__ wbT)
{
    __shared__ u16 sT[128][136];
    const int bid = blockIdx.x, t = threadIdx.x;
    if (bid < 1024) {
        int idx = (bid << 8) | t;
        int j = idx >> 14, k = (idx >> 7) & 127, l = idx & 127;
        float v = Do[j*K_ + k] * Di[j*L_ + l] * product[k*L_ + l];
        if (k < M1_ && l < M1_) {
            float q = 0.f;
            #pragma unroll
            for (int r = 0; r < R_; ++r)
                q += A[(j*R_ + r)*M1_ + k] * Bm[(j*R_ + r)*M1_ + l];
            v += q;
        }
        Hkl[idx] = f2bf(v);
    } else if (bid < 2048) {
        int idx = ((bid - 1024) << 8) | t;
        int o = idx >> 11, ji = idx & 2047, j = ji >> 7, i = ji & 127;
        W2T[idx] = f2bf(W[(i*DIM + o)*J_ + j]);
    } else {
        const int p0 = (bid - 2048) * 128;
        #pragma unroll
        for (int it = 0; it < 16; ++it) {
            int idx = it*256 + t, row = idx >> 5, c4 = (idx & 31) * 4;
            float4 v = *(const float4*)(wb + (size_t)(p0+row)*L_ + c4);
            sT[c4+0][row] = f2bf(v.x); sT[c4+1][row] = f2bf(v.y);
            sT[c4+2][row] = f2bf(v.z); sT[c4+3][row] = f2bf(v.w);
        }
        __syncthreads();
        #pragma unroll
        for (int it = 0; it < 8; ++it) {
            int idx = it*256 + t, l = idx >> 4, pc = (idx & 15) * 8;
            *(u16x8*)(wbT + (size_t)l*NPTS + p0 + pc) = *(const u16x8*)&sT[l][pc];
        }
    }
}

// ---------------------------------------------------------------------------
// Stage A: part[ks][bi][l] = sum_{p in 2048-chunk} x[bi][p]*wbT[l][p]
// grid (64 m-tiles of 32, 8 k-splits) = 512 blocks (2 blocks/CU), 256 thr
// (4 waves side-by-side, wave-tile 32x32), BK=128, register double-buffer.
__global__ __launch_bounds__(256) void k_stageA(
    const float* __restrict__ x, const u16* __restrict__ wbT,
    float* __restrict__ part)
{
    __shared__ u16 sA[32][136];    // [m][p]
    __shared__ u16 sB[128][136];   // [l][p]
    const int t = threadIdx.x, lane = t & 63, wave = t >> 6;
    const int quad = lane >> 4, l16 = lane & 15;
    const int m0 = blockIdx.x * 32;
    const size_t pbase = (size_t)blockIdx.y * 2048;

    f32x4 acc[2][2] = {};
    const int ac4 = (t & 31) * 4, arr = t >> 5;    // x: 4 float4/thread (rows 0..7 +8i)
    const int bc8 = (t & 15) * 8, brr = t >> 4;    // wbT: 8 u16x8/thread (rows 0..15 +16i)

    float4 ra[4];
    u16x8  rb[8];
    #pragma unroll
    for (int i = 0; i < 4; ++i)
        ra[i] = *(const float4*)(x + (size_t)(m0 + arr + 8*i)*NPTS + pbase + ac4);
    #pragma unroll
    for (int i = 0; i < 8; ++i)
        rb[i] = *(const u16x8*)(wbT + (size_t)(brr + 16*i)*NPTS + pbase + bc8);

    for (int pc = 0; pc < 2048; pc += 128) {
        #pragma unroll
        for (int i = 0; i < 4; ++i) {
            u16x4 h = { f2bf(ra[i].x), f2bf(ra[i].y), f2bf(ra[i].z), f2bf(ra[i].w) };
            *(u16x4*)&sA[arr + 8*i][ac4] = h;
        }
        #pragma unroll
        for (int i = 0; i < 8; ++i)
            *(u16x8*)&sB[brr + 16*i][bc8] = rb[i];
        __syncthreads();
        if (pc + 128 < 2048) {
            #pragma unroll
            for (int i = 0; i < 4; ++i)
                ra[i] = *(const float4*)(x + (size_t)(m0 + arr + 8*i)*NPTS + pbase + pc + 128 + ac4);
            #pragma unroll
            for (int i = 0; i < 8; ++i)
                rb[i] = *(const u16x8*)(wbT + (size_t)(brr + 16*i)*NPTS + pbase + pc + 128 + bc8);
        }
        #pragma unroll
        for (int ks = 0; ks < 4; ++ks) {
            int kb = ks*32 + quad*8;
            s16x8 a0 = *(const s16x8*)&sA[l16][kb];
            s16x8 a1 = *(const s16x8*)&sA[16 + l16][kb];
            s16x8 b0 = *(const s16x8*)&sB[wave*32      + l16][kb];
            s16x8 b1 = *(const s16x8*)&sB[wave*32 + 16 + l16][kb];
            acc[0][0] = MFMA16(a0, b0, acc[0][0]);
            acc[0][1] = MFMA16(a0, b1, acc[0][1]);
            acc[1][0] = MFMA16(a1, b0, acc[1][0]);
            acc[1][1] = MFMA16(a1, b1, acc[1][1]);
        }
        __syncthreads();
    }
    float* po = part + (size_t)blockIdx.y * (2048*128);
    #pragma unroll
    for (int mt = 0; mt < 2; ++mt)
      #pragma unroll
      for (int r = 0; r < 4; ++r) {
        int row = m0 + mt*16 + quad*4 + r;
        #pragma unroll
        for (int nt = 0; nt < 2; ++nt) {
            int col = wave*32 + nt*16 + l16;
            po[(size_t)row*128 + col] = acc[mt][nt][r];
        }
      }
}

// xhatb[bi][l] = bf16( sum of 8 partials )
__global__ __launch_bounds__(256) void k_reduceA(
    const float* __restrict__ part, u16* __restrict__ xhatb)
{
    int i = blockIdx.x * 1024 + threadIdx.x;
    #pragma unroll
    for (int e = 0; e < 4; ++e, i += 256) {
        float s = 0.f;
        #pragma unroll
        for (int p = 0; p < 8; ++p) s += part[p*262144 + i];
        xhatb[i] = f2bf(s);
    }
}

// ---------------------------------------------------------------------------
// Fused mix: per (b,j) block,
//   phase1: P[k][i] = sum_l Hkl[j][k][l] * xhatb[b*128+i][l]    (MFMA)
//   phase2: ypartb[j][b][o][k] = sum_i W2T[o][j*128+i] * P[k][i] (MFMA)
__global__ __launch_bounds__(256) void k_mixF(
    const u16* __restrict__ Hkl, const u16* __restrict__ xhatb,
    const u16* __restrict__ W2T, u16* __restrict__ ypartb)
{
    __shared__ u16 sA[128][136];   // phase1: [k][l] Hkl;   phase2: [k][i] P
    __shared__ u16 sB[128][136];   // phase1: [i][l] xhat;  phase2: [o][i] W2T
    const int t = threadIdx.x, lane = t & 63, wave = t >> 6;
    const int quad = lane >> 4, l16 = lane & 15;
    const int wr = wave >> 1, wc = wave & 1;
    const int b = blockIdx.x, j = blockIdx.y;
    const u16* ha = Hkl + j*16384;
    const u16* xb = xhatb + b*16384;

    const int c8 = (t & 15)*8, rr = t >> 4;
    #pragma unroll
    for (int i = 0; i < 8; ++i) {
        int row = rr + 16*i;
        *(u16x8*)&sA[row][c8] = *(const u16x8*)(ha + row*128 + c8);
        *(u16x8*)&sB[row][c8] = *(const u16x8*)(xb + row*128 + c8);
    }
    __syncthreads();

    f32x4 acc1[4][4] = {};
    #pragma unroll
    for (int ks = 0; ks < 4; ++ks) {
        int kb = ks*32 + quad*8;
        s16x8 a[4], bf[4];
        #pragma unroll
        for (int mt = 0; mt < 4; ++mt) a[mt]  = *(const s16x8*)&sA[wr*64 + mt*16 + l16][kb];
        #pragma unroll
        for (int nt = 0; nt < 4; ++nt) bf[nt] = *(const s16x8*)&sB[wc*64 + nt*16 + l16][kb];
        #pragma unroll
        for (int mt = 0; mt < 4; ++mt)
            #pragma unroll
            for (int nt = 0; nt < 4; ++nt)
                acc1[mt][nt] = MFMA16(a[mt], bf[nt], acc1[mt][nt]);
    }
    __syncthreads();   // phase-1 LDS reads done; safe to overwrite

    #pragma unroll
    for (int mt = 0; mt < 4; ++mt)
      #pragma unroll
      for (int r = 0; r < 4; ++r) {
        int k = wr*64 + mt*16 + quad*4 + r;
        #pragma unroll
        for (int nt = 0; nt < 4; ++nt)
            sA[k][wc*64 + nt*16 + l16] = f2bf(acc1[mt][nt][r]);
      }
    #pragma unroll
    for (int i = 0; i < 8; ++i) {
        int row = rr + 16*i;
        *(u16x8*)&sB[row][c8] = *(const u16x8*)(W2T + (size_t)row*2048 + j*128 + c8);
    }
    __syncthreads();

    f32x4 acc2[4][4] = {};
    #pragma unroll
    for (int ks = 0; ks < 4; ++ks) {
        int kb = ks*32 + quad*8;
        s16x8 a[4], bf[4];
        #pragma unroll
        for (int mt = 0; mt < 4; ++mt) a[mt]  = *(const s16x8*)&sB[wr*64 + mt*16 + l16][kb];
        #pragma unroll
        for (int nt = 0; nt < 4; ++nt) bf[nt] = *(const s16x8*)&sA[wc*64 + nt*16 + l16][kb];
        #pragma unroll
        for (int mt = 0; mt < 4; ++mt)
            #pragma unroll
            for (int nt = 0; nt < 4; ++nt)
                acc2[mt][nt] = MFMA16(a[mt], bf[nt], acc2[mt][nt]);
    }
    u16* yo = ypartb + ((size_t)(j*16 + b) << 14);
    #pragma unroll
    for (int mt = 0; mt < 4; ++mt)
      #pragma unroll
      for (int r = 0; r < 4; ++r) {
        int o = wr*64 + mt*16 + quad*4 + r;
        #pragma unroll
        for (int nt = 0; nt < 4; ++nt) {
            int k = wc*64 + nt*16 + l16;
            yo[(size_t)o*128 + k] = f2bf(acc2[mt][nt][r]);
        }
      }
}

// yb[bo][k] = bf16( sum of 16 bf16 partials ), vectorized u16x8
__global__ __launch_bounds__(256) void k_reduceY(
    const u16* __restrict__ part, u16* __restrict__ yb)
{
    int i8 = (blockIdx.x * 256 + threadIdx.x) * 8;
    float s[8] = {};
    #pragma unroll
    for (int p = 0; p < 16; ++p) {
        u16x8 v = *(const u16x8*)(part + p*262144 + i8);
        #pragma unroll
        for (int e = 0; e < 8; ++e) s[e] += bf2f(v[e]);
    }
    u16x8 o;
    #pragma unroll
    for (int e = 0; e < 8; ++e) o[e] = f2bf(s[e]);
    *(u16x8*)(yb + i8) = o;
}

// ---------------------------------------------------------------------------
// Stage E: out[bo][p] = sum_k yb[bo][k] * bases[p][k]  (bases f32, inline cvt)
__global__ __launch_bounds__(256) void k_stageE(
    const u16* __restrict__ yb, const float* __restrict__ bases,
    float* __restrict__ out)
{
    __shared__ u16 sA[128][136];   // [bo][k]
    __shared__ u16 sB[128][136];   // [p][k]
    const int t = threadIdx.x, lane = t & 63, wave = t >> 6;
    const int quad = lane >> 4, l16 = lane & 15;
    const int wr = wave >> 1, wc = wave & 1;
    const int bo0 = blockIdx.x * 128, p0 = blockIdx.y * 128;

    const int c8 = (t & 15)*8, rr = t >> 4;
    #pragma unroll
    for (int i = 0; i < 8; ++i) {
        int row = rr + 16*i;
        *(u16x8*)&sA[row][c8] = *(const u16x8*)(yb + (size_t)(bo0+row)*128 + c8);
    }
    const int c4 = (t & 31) * 4, br = t >> 5;
    #pragma unroll
    for (int i = 0; i < 16; ++i) {
        int row = br + 8*i;
        float4 v = *(const float4*)(bases + (size_t)(p0+row)*K_ + c4);
        u16x4 h = { f2bf(v.x), f2bf(v.y), f2bf(v.z), f2bf(v.w) };
        *(u16x4*)&sB[row][c4] = h;
    }
    __syncthreads();

    f32x4 acc[4][4] = {};
    #pragma unroll
    for (int ks = 0; ks < 4; ++ks) {
        int kb = ks*32 + quad*8;
        s16x8 a[4], bf[4];
        #pragma unroll
        for (int mt = 0; mt < 4; ++mt) a[mt]  = *(const s16x8*)&sA[wr*64 + mt*16 + l16][kb];
        #pragma unroll
        for (int nt = 0; nt < 4; ++nt) bf[nt] = *(const s16x8*)&sB[wc*64 + nt*16 + l16][kb];
        #pragma unroll
        for (int mt = 0; mt < 4; ++mt)
            #pragma unroll
            for (int nt = 0; nt < 4; ++nt)
                acc[mt][nt] = MFMA16(a[mt], bf[nt], acc[mt][nt]);
    }
    #pragma unroll
    for (int mt = 0; mt < 4; ++mt)
      #pragma unroll
      for (int r = 0; r < 4; ++r) {
        size_t row = bo0 + wr*64 + mt*16 + quad*4 + r;
        #pragma unroll
        for (int nt = 0; nt < 4; ++nt) {
            int p = p0 + wc*64 + nt*16 + l16;
            out[row*NPTS + p] = acc[mt][nt][r];
        }
      }
}

// ---------------------------------------------------------------------------
extern "C" void kernel_launch(void* const* d_in, const int* in_sizes, int n_in,
                              void* d_out, int out_size, void* d_ws, size_t ws_size,
                              hipStream_t stream) {
    (void)in_sizes; (void)n_in; (void)out_size; (void)ws_size;
    const float* x       = (const float*)d_in[0];
    const float* bases   = (const float*)d_in[1];
    const float* wbases  = (const float*)d_in[2];
    const float* product = (const float*)d_in[3];
    const float* Do      = (const float*)d_in[4];
    const float* Di      = (const float*)d_in[5];
    const float* A       = (const float*)d_in[6];
    const float* Bm      = (const float*)d_in[7];
    const float* W       = (const float*)d_in[8];

    char* ws = (char*)d_ws;
    float* partA  = (float*)(ws + OFF_PARTA);
    u16*   wbT    = (u16*)  (ws + OFF_WBT);
    u16*   Hkl    = (u16*)  (ws + OFF_HKL);
    u16*   W2T    = (u16*)  (ws + OFF_W2T);
    u16*   xhatb  = (u16*)  (ws + OFF_XHB);
    u16*   yb     = (u16*)  (ws + OFF_YB);
    u16*   ypartb = (u16*)  (ws + OFF_YPB);

    k_prep   <<<2176, 256, 0, stream>>>(product, Do, Di, A, Bm, W, wbases,
                                        Hkl, W2T, wbT);
    k_stageA <<<dim3(64, 8), 256, 0, stream>>>(x, wbT, partA);
    k_reduceA<<<256, 256, 0, stream>>>(partA, xhatb);
    k_mixF   <<<dim3(16, 16), 256, 0, stream>>>(Hkl, xhatb, W2T, ypartb);
    k_reduceY<<<128, 256, 0, stream>>>(ypartb, yb);
    k_stageE <<<dim3(16, 128), 256, 0, stream>>>(yb, bases, (float*)d_out);
}